// Round 7
// baseline (363.701 us; speedup 1.0000x reference)
//
#include <hip/hip_runtime.h>
#include <hip/hip_bf16.h>

typedef __hip_bfloat16 bf16;
typedef short bf16x8_t __attribute__((ext_vector_type(8)));  // 8 bf16 = 4 VGPRs
typedef float f32x4_t __attribute__((ext_vector_type(4)));

#define NTOK 8192
#define INF  1024
#define OUTF 1024
#define GS   8
#define KTOT (INF + INF * GS)  // 9216

union b8u { bf16 h[8]; bf16x8_t v; };
union b4u { bf16 h[4]; ushort2 v2[2]; };

// ---------------- prep A: A[n,k] = bf16[ silu(x) | exp(-|x-grid_g|) ] ----------------
// R6 known-good: 1 elem/thread, all stores lane-contiguous, grid read as row-0
// broadcast (reference builds grid via broadcast_to -> rows identical).
__global__ __launch_bounds__(256) void prep_a(const float* __restrict__ x,
                                              const float* __restrict__ grid,
                                              bf16* __restrict__ A) {
  const int idx = blockIdx.x * 256 + threadIdx.x;  // n*INF + i
  const int i = idx & (INF - 1);
  const int n = idx >> 10;
  const float xv = x[idx];
  const float s = xv / (1.0f + __expf(-xv));       // SiLU
  const size_t rowb = (size_t)n * KTOT;
  A[rowb + i] = __float2bfloat16(s);
  b8u kn;
  #pragma unroll
  for (int g = 0; g < 8; ++g) {
    const float gv = grid[g];                      // row 0 == row i (broadcast_to)
    kn.h[g] = __float2bfloat16(__expf(-fabsf(xv - gv)));  // sigma = 1
  }
  *(bf16x8_t*)(A + rowb + INF + (size_t)i * 8) = kn.v;   // 16B lane-contiguous
}

// ---------------- prep B: B[o,k] = bf16[ base_w | spline_w * scaler ] ----------------
// R6 known-good: 2 threads per (o,i), sw loads 16B/lane contiguous, spline stores
// 8B/lane contiguous, ss broadcast-pair, bw on even lanes.
__global__ __launch_bounds__(256) void prep_b(const float* __restrict__ bw,
                                              const float* __restrict__ sw,
                                              const float* __restrict__ ss,
                                              bf16* __restrict__ B) {
  const int tid = blockIdx.x * 256 + threadIdx.x;  // 0 .. OUTF*INF*2-1
  const int o = tid >> 11;                         // 2048 threads per o-row
  const int r = tid & 2047;                        // i*2 + half
  const float4 w4 = ((const float4*)sw)[tid];      // 4 of the 8 g-values of (o,i)
  const float sc = ss[tid >> 1];
  b4u r4;
  r4.h[0] = __float2bfloat16(w4.x * sc);
  r4.h[1] = __float2bfloat16(w4.y * sc);
  r4.h[2] = __float2bfloat16(w4.z * sc);
  r4.h[3] = __float2bfloat16(w4.w * sc);
  const size_t rowb = (size_t)o * KTOT;
  *(ushort2*)(B + rowb + INF + (size_t)r * 4)     = r4.v2[0];  // 8B contiguous
  *(ushort2*)(B + rowb + INF + (size_t)r * 4 + 2) = r4.v2[1];
  if ((tid & 1) == 0)                              // even lanes: base weight
    B[rowb + (r >> 1)] = __float2bfloat16(bw[tid >> 1]);
}

// ---------------- zero C (d_out is poisoned 0xAA before every launch) ----------------
__global__ __launch_bounds__(256) void zero_c(float* __restrict__ C) {
  const int idx = blockIdx.x * 256 + threadIdx.x;
  *(float4*)(C + (size_t)idx * 4) = float4{0.f, 0.f, 0.f, 0.f};
}

// ---------------- GEMM: C[M,N] += A[M,K] * B[N,K]^T, split-K=3 ----------------
// m97 recipe + XOR LDS swizzle (R3: conflicts 5.7e7 -> 0). 128x128 block tile, BK=64,
// 4 waves 2x2, each wave 64x64 = 4x4 tiles of 16x16x32 bf16. global_load_lds width 16.
// Split-K=3 (THE one change vs R6): grid 512 -> 1536 = 2 exact rounds of 3 blocks/CU
// (144 regs/wave -> 3 waves/SIMD cap; R4's split-K=2 was 768+256 ragged + confounded).
// The 3 kv-siblings of a C-tile are 512 apart in linear id -> same id%8 -> same XCD L2
// for the atomic accumulation.
#define BM 128
#define BN 128
#define BK 64
#define KSPLIT 3
#define KSEG (KTOT / KSPLIT)  // 3072 = 48 BK-iters

__global__ __launch_bounds__(256) void gemm_bt(const bf16* __restrict__ A,
                                               const bf16* __restrict__ B,
                                               float* __restrict__ C) {
  __shared__ bf16 sA[BM * BK];
  __shared__ bf16 sB[BN * BK];

  const int t = threadIdx.x;
  const int lane = t & 63;
  const int w = t >> 6;            // wave 0..3
  const int wm = (w >> 1) * 64;    // wave quadrant row
  const int wn = (w & 1) * 64;     // wave quadrant col
  const int bc = blockIdx.x;       // N tile (0..7)
  const int br = blockIdx.y;       // M tile (0..63)
  const int kv = blockIdx.z;       // K segment (0..2)

  // staging: thread t fills LDS slot (srow, chunk c) at byte offset t*16.
  // XOR swizzle: slot (srow, c) holds global k-chunk kc = c ^ (srow&7).
  const int srow = t >> 3;                         // 0..31 (x4 insts -> 128 rows)
  const int scol = ((t & 7) ^ (srow & 7)) * 8;     // swizzled source k-offset (elems)
  const bf16* gA = A + (size_t)(br * BM + srow) * KTOT + scol;
  const bf16* gB = B + (size_t)(bc * BN + srow) * KTOT + scol;
  char* sAb = (char*)sA + w * 1024;  // wave-uniform dest base (+ lane*16 implicit)
  char* sBb = (char*)sB + w * 1024;

  // fragment addressing: A[m=lane&15][k=(lane>>4)*8 + j]
  const int frow = lane & 15;
  const int fk = (lane >> 4) * 8;
  const int fsw = frow & 7;        // row&7 identical for all fragment rows (offsets 0 mod 8)

  f32x4_t acc[4][4] = {};

  const int kbeg = kv * KSEG;
  const int kend = kbeg + KSEG;
  for (int k0 = kbeg; k0 < kend; k0 += BK) {
    #pragma unroll
    for (int inst = 0; inst < 4; ++inst) {   // +32 rows per inst: (row&7) unchanged
      __builtin_amdgcn_global_load_lds(
          (const __attribute__((address_space(1))) void*)(gA + (size_t)inst * 32 * KTOT + k0),
          (__attribute__((address_space(3))) void*)(sAb + inst * 4096), 16, 0, 0);
      __builtin_amdgcn_global_load_lds(
          (const __attribute__((address_space(1))) void*)(gB + (size_t)inst * 32 * KTOT + k0),
          (__attribute__((address_space(3))) void*)(sBb + inst * 4096), 16, 0, 0);
    }
    __syncthreads();
    #pragma unroll
    for (int kk = 0; kk < BK; kk += 32) {
      const int swk = ((((kk + fk) >> 3) ^ fsw) * 8);  // swizzled chunk -> elem offset
      bf16x8_t af[4], bf_[4];
      #pragma unroll
      for (int i = 0; i < 4; ++i) {
        af[i]  = *(const bf16x8_t*)(sA + (wm + i * 16 + frow) * BK + swk);
        bf_[i] = *(const bf16x8_t*)(sB + (wn + i * 16 + frow) * BK + swk);
      }
      #pragma unroll
      for (int i = 0; i < 4; ++i)
        #pragma unroll
        for (int j = 0; j < 4; ++j)
          acc[i][j] = __builtin_amdgcn_mfma_f32_16x16x32_bf16(af[i], bf_[j], acc[i][j], 0, 0, 0);
    }
    __syncthreads();
  }

  // epilogue: D mapping col = lane&15, row = (lane>>4)*4 + reg  [m89/m91]
  // split-K partial sums -> fp32 atomicAdd into zeroed C (device-scope by default)
  const int ccol = bc * BN + wn + frow;
  const int crow0 = br * BM + wm + (lane >> 4) * 4;
  #pragma unroll
  for (int i = 0; i < 4; ++i)
    #pragma unroll
    for (int r = 0; r < 4; ++r) {
      float* cp = C + (size_t)(crow0 + i * 16 + r) * OUTF + ccol;
      #pragma unroll
      for (int j = 0; j < 4; ++j)
        atomicAdd(cp + j * 16, acc[i][j][r]);
    }
}

// ---------------- fallback (ws too small): naive, correctness-only ----------------
__global__ __launch_bounds__(256) void naive_kern(const float* __restrict__ x,
                                                  const float* __restrict__ bw,
                                                  const float* __restrict__ sw,
                                                  const float* __restrict__ ss,
                                                  const float* __restrict__ grid,
                                                  float* __restrict__ out) {
  const int idx = blockIdx.x * 256 + threadIdx.x;  // n*OUTF + o
  const int o = idx & (OUTF - 1);
  const int n = idx >> 10;
  float acc = 0.f;
  for (int i = 0; i < INF; ++i) {
    const float xv = x[n * INF + i];
    const float s = xv / (1.f + __expf(-xv));
    acc += s * bw[o * INF + i];
    const float sc = ss[o * INF + i];
    #pragma unroll
    for (int g = 0; g < 8; ++g) {
      const float gv = grid[i * 8 + g];
      acc += __expf(-fabsf(xv - gv)) * sw[(size_t)(o * INF + i) * 8 + g] * sc;
    }
  }
  out[idx] = acc;
}

extern "C" void kernel_launch(void* const* d_in, const int* in_sizes, int n_in,
                              void* d_out, int out_size, void* d_ws, size_t ws_size,
                              hipStream_t stream) {
  const float* x    = (const float*)d_in[0];
  const float* bw   = (const float*)d_in[1];
  const float* sw   = (const float*)d_in[2];
  const float* ss   = (const float*)d_in[3];
  const float* grid = (const float*)d_in[4];
  float* out = (float*)d_out;

  const size_t needA = (size_t)NTOK * KTOT * sizeof(bf16);  // ~151 MB
  const size_t needB = (size_t)OUTF * KTOT * sizeof(bf16);  // ~19 MB

  if (ws_size >= needA + needB) {
    bf16* A = (bf16*)d_ws;
    bf16* B = (bf16*)((char*)d_ws + needA);
    prep_a<<<(NTOK * INF) / 256, 256, 0, stream>>>(x, grid, A);
    prep_b<<<(OUTF * INF * 2) / 256, 256, 0, stream>>>(bw, sw, ss, B);
    zero_c<<<(NTOK * OUTF) / 1024, 256, 0, stream>>>(out);
    dim3 g(OUTF / BN, NTOK / BM, KSPLIT);  // (8, 64, 3) = 1536 blocks
    gemm_bt<<<g, 256, 0, stream>>>(A, B, out);
  } else {
    naive_kern<<<(NTOK * OUTF) / 256, 256, 0, stream>>>(x, bw, sw, ss, grid, out);
  }
}

// Round 8
// 309.971 us; speedup vs baseline: 1.1733x; 1.1733x over previous
//
#include <hip/hip_runtime.h>
#include <hip/hip_bf16.h>

typedef __hip_bfloat16 bf16;
typedef short bf16x8_t __attribute__((ext_vector_type(8)));  // 8 bf16 = 4 VGPRs
typedef float f32x4_t __attribute__((ext_vector_type(4)));

#define NTOK 8192
#define INF  1024
#define OUTF 1024
#define GS   8
#define KTOT (INF + INF * GS)  // 9216

union b8u { bf16 h[8]; bf16x8_t v; };
union b4u { bf16 h[4]; ushort2 v2[2]; };

// ---------------- fused prep (R6 access patterns, verbatim; one dispatch) ----------
// Blocks [0, PA): A[n,k] = bf16[ silu(x) | exp(-|x-grid_g|) ]  -- R6 prep_a body.
// Blocks [PA, PA+PB): B[o,k] = bf16[ bw | sw*ss ]              -- R6 prep_b body.
// Branch is block-uniform (no divergence). R5 lesson: fusion is safe, pattern
// rewrites are not — bodies below are instruction-identical to R6's two kernels.
#define PA ((NTOK * INF) / 256)       // 32768 blocks
#define PB ((OUTF * INF * 2) / 256)   //  8192 blocks

__global__ __launch_bounds__(256) void prep_fused(const float* __restrict__ x,
                                                  const float* __restrict__ bw,
                                                  const float* __restrict__ sw,
                                                  const float* __restrict__ ss,
                                                  const float* __restrict__ grid,
                                                  bf16* __restrict__ A,
                                                  bf16* __restrict__ B) {
  const int b = blockIdx.x;
  if (b < PA) {
    // ---- R6 prep_a: 1 elem/thread, stores lane-contiguous, grid row-0 broadcast ----
    const int idx = b * 256 + threadIdx.x;         // n*INF + i
    const int i = idx & (INF - 1);
    const int n = idx >> 10;
    const float xv = x[idx];
    const float s = xv / (1.0f + __expf(-xv));     // SiLU
    const size_t rowb = (size_t)n * KTOT;
    A[rowb + i] = __float2bfloat16(s);
    b8u kn;
    #pragma unroll
    for (int g = 0; g < 8; ++g) {
      const float gv = grid[g];                    // row 0 == row i (broadcast_to)
      kn.h[g] = __float2bfloat16(__expf(-fabsf(xv - gv)));  // sigma = 1
    }
    *(bf16x8_t*)(A + rowb + INF + (size_t)i * 8) = kn.v;   // 16B lane-contiguous
  } else {
    // ---- R6 prep_b: 2 threads per (o,i); sw 16B/lane, spline stores 8B/lane ----
    const int tid = (b - PA) * 256 + threadIdx.x;  // 0 .. OUTF*INF*2-1
    const int o = tid >> 11;                       // 2048 threads per o-row
    const int r = tid & 2047;                      // i*2 + half
    const float4 w4 = ((const float4*)sw)[tid];    // 4 of the 8 g-values of (o,i)
    const float sc = ss[tid >> 1];
    b4u r4;
    r4.h[0] = __float2bfloat16(w4.x * sc);
    r4.h[1] = __float2bfloat16(w4.y * sc);
    r4.h[2] = __float2bfloat16(w4.z * sc);
    r4.h[3] = __float2bfloat16(w4.w * sc);
    const size_t rowb = (size_t)o * KTOT;
    *(ushort2*)(B + rowb + INF + (size_t)r * 4)     = r4.v2[0];  // 8B contiguous
    *(ushort2*)(B + rowb + INF + (size_t)r * 4 + 2) = r4.v2[1];
    if ((tid & 1) == 0)                            // even lanes: base weight
      B[rowb + (r >> 1)] = __float2bfloat16(bw[tid >> 1]);
  }
}

// ---------------- GEMM: C[M,N] = A[M,K] * B[N,K]^T  (R3/R6 known-good: 183us, 845TF) --
// m97 recipe + XOR LDS swizzle (R3: conflicts 5.7e7 -> 0). 128x128 block tile, BK=64,
// 4 waves 2x2, each wave 64x64 = 4x4 tiles of 16x16x32 bf16. global_load_lds width 16.
// PLATEAU NOTE (R4+R7 evidence): grid = 512 tiles = exactly 2 blocks/CU. Both routes
// to 3 blocks/CU regressed: split-K=2 (ragged 768+256 tail) and split-K=3 (uniform
// rounds, occupancy 30%, but 64 strided 4B atomics/thread x3 epilogues -> MfmaUtil
// 36.6->30, 183->224us). The barrier-drain stall of this 2-barrier K-loop cannot be
// bought back at this grid granularity; past it = hand-asm-style K-loop restructure
// (m131-m141 all failed from source level).
#define BM 128
#define BN 128
#define BK 64

__global__ __launch_bounds__(256) void gemm_bt(const bf16* __restrict__ A,
                                               const bf16* __restrict__ B,
                                               float* __restrict__ C) {
  __shared__ bf16 sA[BM * BK];
  __shared__ bf16 sB[BN * BK];

  const int t = threadIdx.x;
  const int lane = t & 63;
  const int w = t >> 6;            // wave 0..3
  const int wm = (w >> 1) * 64;    // wave quadrant row
  const int wn = (w & 1) * 64;     // wave quadrant col
  const int bc = blockIdx.x;       // N tile (0..7)
  const int br = blockIdx.y;       // M tile (0..63)

  // staging: thread t fills LDS slot (srow, chunk c) at byte offset t*16.
  // XOR swizzle: slot (srow, c) holds global k-chunk kc = c ^ (srow&7).
  const int srow = t >> 3;                         // 0..31 (x4 insts -> 128 rows)
  const int scol = ((t & 7) ^ (srow & 7)) * 8;     // swizzled source k-offset (elems)
  const bf16* gA = A + (size_t)(br * BM + srow) * KTOT + scol;
  const bf16* gB = B + (size_t)(bc * BN + srow) * KTOT + scol;
  char* sAb = (char*)sA + w * 1024;  // wave-uniform dest base (+ lane*16 implicit)
  char* sBb = (char*)sB + w * 1024;

  // fragment addressing: A[m=lane&15][k=(lane>>4)*8 + j]
  const int frow = lane & 15;
  const int fk = (lane >> 4) * 8;
  const int fsw = frow & 7;        // row&7 identical for all fragment rows (offsets 0 mod 8)

  f32x4_t acc[4][4] = {};

  for (int k0 = 0; k0 < KTOT; k0 += BK) {
    #pragma unroll
    for (int inst = 0; inst < 4; ++inst) {   // +32 rows per inst: (row&7) unchanged
      __builtin_amdgcn_global_load_lds(
          (const __attribute__((address_space(1))) void*)(gA + (size_t)inst * 32 * KTOT + k0),
          (__attribute__((address_space(3))) void*)(sAb + inst * 4096), 16, 0, 0);
      __builtin_amdgcn_global_load_lds(
          (const __attribute__((address_space(1))) void*)(gB + (size_t)inst * 32 * KTOT + k0),
          (__attribute__((address_space(3))) void*)(sBb + inst * 4096), 16, 0, 0);
    }
    __syncthreads();
    #pragma unroll
    for (int kk = 0; kk < BK; kk += 32) {
      const int swk = ((((kk + fk) >> 3) ^ fsw) * 8);  // swizzled chunk -> elem offset
      bf16x8_t af[4], bf_[4];
      #pragma unroll
      for (int i = 0; i < 4; ++i) {
        af[i]  = *(const bf16x8_t*)(sA + (wm + i * 16 + frow) * BK + swk);
        bf_[i] = *(const bf16x8_t*)(sB + (wn + i * 16 + frow) * BK + swk);
      }
      #pragma unroll
      for (int i = 0; i < 4; ++i)
        #pragma unroll
        for (int j = 0; j < 4; ++j)
          acc[i][j] = __builtin_amdgcn_mfma_f32_16x16x32_bf16(af[i], bf_[j], acc[i][j], 0, 0, 0);
    }
    __syncthreads();
  }

  // epilogue: D mapping col = lane&15, row = (lane>>4)*4 + reg  [m89/m91]
  const int ccol = bc * BN + wn + frow;
  const int crow0 = br * BM + wm + (lane >> 4) * 4;
  #pragma unroll
  for (int i = 0; i < 4; ++i)
    #pragma unroll
    for (int r = 0; r < 4; ++r) {
      float* cp = C + (size_t)(crow0 + i * 16 + r) * OUTF + ccol;
      #pragma unroll
      for (int j = 0; j < 4; ++j)
        cp[j * 16] = acc[i][j][r];
    }
}

// ---------------- fallback (ws too small): naive, correctness-only ----------------
__global__ __launch_bounds__(256) void naive_kern(const float* __restrict__ x,
                                                  const float* __restrict__ bw,
                                                  const float* __restrict__ sw,
                                                  const float* __restrict__ ss,
                                                  const float* __restrict__ grid,
                                                  float* __restrict__ out) {
  const int idx = blockIdx.x * 256 + threadIdx.x;  // n*OUTF + o
  const int o = idx & (OUTF - 1);
  const int n = idx >> 10;
  float acc = 0.f;
  for (int i = 0; i < INF; ++i) {
    const float xv = x[n * INF + i];
    const float s = xv / (1.f + __expf(-xv));
    acc += s * bw[o * INF + i];
    const float sc = ss[o * INF + i];
    #pragma unroll
    for (int g = 0; g < 8; ++g) {
      const float gv = grid[i * 8 + g];
      acc += __expf(-fabsf(xv - gv)) * sw[(size_t)(o * INF + i) * 8 + g] * sc;
    }
  }
  out[idx] = acc;
}

extern "C" void kernel_launch(void* const* d_in, const int* in_sizes, int n_in,
                              void* d_out, int out_size, void* d_ws, size_t ws_size,
                              hipStream_t stream) {
  const float* x    = (const float*)d_in[0];
  const float* bw   = (const float*)d_in[1];
  const float* sw   = (const float*)d_in[2];
  const float* ss   = (const float*)d_in[3];
  const float* grid = (const float*)d_in[4];
  float* out = (float*)d_out;

  const size_t needA = (size_t)NTOK * KTOT * sizeof(bf16);  // ~151 MB
  const size_t needB = (size_t)OUTF * KTOT * sizeof(bf16);  // ~19 MB

  if (ws_size >= needA + needB) {
    bf16* A = (bf16*)d_ws;
    bf16* B = (bf16*)((char*)d_ws + needA);
    prep_fused<<<PA + PB, 256, 0, stream>>>(x, bw, sw, ss, grid, A, B);
    dim3 g(OUTF / BN, NTOK / BM);  // (8, 64)
    gemm_bt<<<g, 256, 0, stream>>>(A, B, out);
  } else {
    naive_kern<<<(NTOK * OUTF) / 256, 256, 0, stream>>>(x, bw, sw, ss, grid, out);
  }
}